// Round 1
// baseline (846.084 us; speedup 1.0000x reference)
//
#include <hip/hip_runtime.h>
#include <math.h>

#define F 256
#define BB 4

__device__ __forceinline__ float actf(float x) {
    // x * sigmoid(1.702x) = x / (1 + exp(-1.702x))
    return x / (1.0f + __expf(-1.702f * x));
}

// ---- transpose 6 FxF matrices into workspace (coalesced both sides via LDS tile) ----
__global__ void transpose_k(const float* __restrict__ W0, const float* __restrict__ W1,
                            const float* __restrict__ W2, const float* __restrict__ W3,
                            const float* __restrict__ W4, const float* __restrict__ W5,
                            float* __restrict__ T) {
    __shared__ float tile[32][33];
    const float* W;
    switch (blockIdx.z) {
        case 0: W = W0; break; case 1: W = W1; break; case 2: W = W2; break;
        case 3: W = W3; break; case 4: W = W4; break; default: W = W5; break;
    }
    float* Tz = T + (size_t)blockIdx.z * F * F;
    int x0 = blockIdx.x * 32, y0 = blockIdx.y * 32;
    int tx = threadIdx.x, ty = threadIdx.y; // 32 x 8
    for (int r = ty; r < 32; r += 8)
        tile[r][tx] = W[(size_t)(y0 + r) * F + (x0 + tx)];
    __syncthreads();
    for (int r = ty; r < 32; r += 8)
        Tz[(size_t)(x0 + r) * F + (y0 + tx)] = tile[tx][r];
}

// ---- k_in[b,f] = E[b]*Wkf[f] + bkf[f];  v_in[b,f] = E[b]*Wvf[f] ----
__global__ void embed_init_k(const float* __restrict__ E, const float* __restrict__ Wkf,
                             const float* __restrict__ bkf, const float* __restrict__ Wvf,
                             float* __restrict__ kin, float* __restrict__ vin) {
    int b = blockIdx.x, f = threadIdx.x;
    float e = E[b];
    kin[(size_t)b * F + f] = e * Wkf[f] + bkf[f];
    vin[(size_t)b * F + f] = e * Wvf[f];
}

// ---- out[b,f] = sum_g act?(in[b,g] (+in2[b,g])) * WT[g*F+f] (+bias[f]) ----
template<bool ACT>
__global__ __launch_bounds__(256) void small_gemm_k(
        const float* __restrict__ in, const float* __restrict__ in2,
        const float* __restrict__ WT, const float* __restrict__ bias,
        float* __restrict__ out, int B) {
    __shared__ float s_in[BB][F];
    int b0 = blockIdx.x * BB;
    int f = threadIdx.x;
    int nb = min(BB, B - b0);
    if (nb <= 0) return;
    for (int j = 0; j < nb; ++j) {
        float v = in[(size_t)(b0 + j) * F + f];
        if (in2) v += in2[(size_t)(b0 + j) * F + f];
        s_in[j][f] = ACT ? actf(v) : v;
    }
    for (int j = nb; j < BB; ++j) s_in[j][f] = 0.f;
    __syncthreads();
    float acc[BB] = {0.f, 0.f, 0.f, 0.f};
    #pragma unroll 8
    for (int g = 0; g < F; ++g) {
        float w = WT[(size_t)g * F + f];
        #pragma unroll
        for (int j = 0; j < BB; ++j) acc[j] += s_in[j][g] * w;
    }
    float bb = bias ? bias[f] : 0.f;
    for (int j = 0; j < nb; ++j)
        out[(size_t)(b0 + j) * F + f] = acc[j] + bb;
}

// ---- segment boundaries via binary search (batch_seg is sorted) ----
__global__ void seg_bounds_k(const int* __restrict__ seg, int N, int B, int* __restrict__ start) {
    int i = blockIdx.x * blockDim.x + threadIdx.x;
    int stride = gridDim.x * blockDim.x;
    for (int b = i; b <= B; b += stride) {
        int lo = 0, hi = N;
        while (lo < hi) { int mid = (lo + hi) >> 1; if (seg[mid] < b) lo = mid + 1; else hi = mid; }
        start[b] = lo;
    }
}

// ---- dot[i] = x_i . kp[seg_i] ; one row per wave, float4 per lane ----
__global__ __launch_bounds__(256) void dot_k(
        const float* __restrict__ x, const float* __restrict__ kp,
        const int* __restrict__ seg, float* __restrict__ dotv, int N) {
    int gtid = blockIdx.x * blockDim.x + threadIdx.x;
    int wid = gtid >> 6, lane = gtid & 63;
    int nw = (gridDim.x * blockDim.x) >> 6;
    for (int r = wid; r < N; r += nw) {
        int s = seg[r];
        float4 xv = *((const float4*)(x + (size_t)r * F) + lane);
        float4 kv = *((const float4*)(kp + (size_t)s * F) + lane);
        float d = xv.x * kv.x + xv.y * kv.y + xv.z * kv.z + xv.w * kv.w;
        #pragma unroll
        for (int o = 32; o > 0; o >>= 1) d += __shfl_xor(d, o, 64);
        if (lane == 0) dotv[r] = d;
    }
}

// ---- per-segment max and sum(exp((dot-max)/16)) ; one block per segment ----
__global__ __launch_bounds__(256) void seg_reduce_k(
        const float* __restrict__ dotv, const int* __restrict__ start,
        float* __restrict__ mv, float* __restrict__ av) {
    int b = blockIdx.x;
    int s = start[b], e = start[b + 1];
    int tid = threadIdx.x;
    __shared__ float red[4];
    float lmax = -INFINITY;
    for (int i = s + tid; i < e; i += 256) lmax = fmaxf(lmax, dotv[i]);
    #pragma unroll
    for (int o = 32; o > 0; o >>= 1) lmax = fmaxf(lmax, __shfl_xor(lmax, o, 64));
    if ((tid & 63) == 0) red[tid >> 6] = lmax;
    __syncthreads();
    float mm = fmaxf(fmaxf(red[0], red[1]), fmaxf(red[2], red[3]));
    float lsum = 0.f;
    for (int i = s + tid; i < e; i += 256) lsum += __expf((dotv[i] - mm) * 0.0625f);
    #pragma unroll
    for (int o = 32; o > 0; o >>= 1) lsum += __shfl_xor(lsum, o, 64);
    __syncthreads();
    if ((tid & 63) == 0) red[tid >> 6] = lsum;
    __syncthreads();
    if (tid == 0) { mv[b] = mm; av[b] = red[0] + red[1] + red[2] + red[3]; }
}

// ---- out[i,:] = (exp((dot_i - m[seg])/16) / (anorm[seg]+eps)) * v_mol[seg] ----
__global__ __launch_bounds__(256) void out_k(
        const float* __restrict__ dotv, const float* __restrict__ mv,
        const float* __restrict__ av, const float* __restrict__ vmol,
        const int* __restrict__ seg, float* __restrict__ out, int N) {
    int gtid = blockIdx.x * blockDim.x + threadIdx.x;
    int wid = gtid >> 6, lane = gtid & 63;
    int nw = (gridDim.x * blockDim.x) >> 6;
    for (int r = wid; r < N; r += nw) {
        int s = seg[r];
        float scale = __expf((dotv[r] - mv[s]) * 0.0625f) / (av[s] + 1e-8f);
        float4 vv = *((const float4*)(vmol + (size_t)s * F) + lane);
        float4 o;
        o.x = scale * vv.x; o.y = scale * vv.y; o.z = scale * vv.z; o.w = scale * vv.w;
        *((float4*)(out + (size_t)r * F) + lane) = o;
    }
}

extern "C" void kernel_launch(void* const* d_in, const int* in_sizes, int n_in,
                              void* d_out, int out_size, void* d_ws, size_t ws_size,
                              hipStream_t stream) {
    const float* x        = (const float*)d_in[0];
    const float* E        = (const float*)d_in[1];
    const int*   batchseg = (const int*)d_in[3];
    const float* Wq       = (const float*)d_in[4];
    const float* Wkf      = (const float*)d_in[5];
    const float* bkf      = (const float*)d_in[6];
    const float* Wvf      = (const float*)d_in[7];
    const float* kW1      = (const float*)d_in[8];
    const float* kb1      = (const float*)d_in[9];
    const float* kW2      = (const float*)d_in[10];
    const float* kb2      = (const float*)d_in[11];
    const float* kWo      = (const float*)d_in[12];
    const float* kbo      = (const float*)d_in[13];
    const float* vW1      = (const float*)d_in[14];
    const float* vW2      = (const float*)d_in[15];
    const float* vWo      = (const float*)d_in[16];
    float* out = (float*)d_out;

    int N = in_sizes[0] / F;
    int B = in_sizes[1];

    // workspace layout (all f32 unless noted)
    float* ws   = (float*)d_ws;
    size_t BF   = (size_t)B * F;
    float* kinK = ws;
    float* kinV = kinK + BF;
    float* h1   = kinV + BF;
    float* h2   = h1 + BF;
    float* kmol = h2 + BF;
    float* vmol = kmol + BF;
    float* kp   = vmol + BF;
    float* WT   = kp + BF;          // 6 * F*F
    float* kW1T = WT;
    float* kW2T = WT + 1 * F * F;
    float* kWoT = WT + 2 * F * F;
    float* vW1T = WT + 3 * F * F;
    float* vW2T = WT + 4 * F * F;
    float* vWoT = WT + 5 * F * F;
    float* dotv = WT + 6 * F * F;   // N
    float* mv   = dotv + N;         // B
    float* av   = mv + B;           // B
    int*   stb  = (int*)(av + B);   // B+1

    // 1) transpose the six W.T matrices (coalesced inner loops downstream)
    transpose_k<<<dim3(F / 32, F / 32, 6), dim3(32, 8), 0, stream>>>(kW1, kW2, kWo, vW1, vW2, vWo, WT);
    // 2) embedding init
    embed_init_k<<<B, F, 0, stream>>>(E, Wkf, bkf, Wvf, kinK, kinV);
    // 3) the two resMLPs + kp = k_mol @ Wq (Wq used untransposed by construction)
    int gg = (B + BB - 1) / BB;
    small_gemm_k<true ><<<gg, 256, 0, stream>>>(kinK, nullptr, kW1T, kb1, h1, B);
    small_gemm_k<true ><<<gg, 256, 0, stream>>>(h1,   nullptr, kW2T, kb2, h2, B);
    small_gemm_k<true ><<<gg, 256, 0, stream>>>(h2,   kinK,    kWoT, kbo, kmol, B);
    small_gemm_k<true ><<<gg, 256, 0, stream>>>(kinV, nullptr, vW1T, nullptr, h1, B);
    small_gemm_k<true ><<<gg, 256, 0, stream>>>(h1,   nullptr, vW2T, nullptr, h2, B);
    small_gemm_k<true ><<<gg, 256, 0, stream>>>(h2,   kinV,    vWoT, nullptr, vmol, B);
    small_gemm_k<false><<<gg, 256, 0, stream>>>(kmol, nullptr, Wq,   nullptr, kp, B);
    // 4) segment boundaries (batch_seg sorted)
    seg_bounds_k<<<2, 256, 0, stream>>>(batchseg, N, B, stb);
    // 5) dot pass (reads x once — the only big read)
    dot_k<<<2048, 256, 0, stream>>>(x, kp, batchseg, dotv, N);
    // 6) per-segment softmax stats
    seg_reduce_k<<<B, 256, 0, stream>>>(dotv, stb, mv, av);
    // 7) output pass (the only big write)
    out_k<<<2048, 256, 0, stream>>>(dotv, mv, av, vmol, batchseg, out, N);
}